// Round 1
// baseline (518.885 us; speedup 1.0000x reference)
//
#include <hip/hip_runtime.h>
#include <math.h>

#define D      2048
#define NR     32
#define MROWS  16
#define HSS    2052          // padded bf16 elems per LDS row
#define HSSU   (HSS / 2)     // 1026 uints per row

__device__ __forceinline__ unsigned int f2bf(float f) {
    unsigned int u = __float_as_uint(f);
    return (u + 0x7FFFu + ((u >> 16) & 1u)) >> 16;   // RNE bf16, low 16 bits
}
__device__ __forceinline__ float bflo(unsigned int p) { return __uint_as_float(p << 16); }
__device__ __forceinline__ float bfhi(unsigned int p) { return __uint_as_float(p & 0xFFFF0000u); }

__device__ __forceinline__ void fma4(float a, const float4& w, float4& o) {
    o.x = fmaf(a, w.x, o.x);
    o.y = fmaf(a, w.y, o.y);
    o.z = fmaf(a, w.z, o.z);
    o.w = fmaf(a, w.w, o.w);
}

__global__ __launch_bounds__(256, 2)
void adapter_fused(const float* __restrict__ x,
                   const float* __restrict__ gamma,
                   const float* __restrict__ beta,
                   const float* __restrict__ wd,
                   const float* __restrict__ bd,
                   const float* __restrict__ wu,
                   const float* __restrict__ bu,
                   float* __restrict__ out)
{
    __shared__ unsigned int hs[MROWS * HSSU];   // normalized h, bf16-packed
    __shared__ float yacc[MROWS * NR];          // down-proj accumulator
    __shared__ float amat[MROWS * NR];          // gelu output

    const int tid = threadIdx.x;
    const long row0 = (long)blockIdx.x * MROWS;

    yacc[tid] = 0.0f;
    yacc[tid + 256] = 0.0f;

    // ---------------- Phase A: LayerNorm -> hs (bf16 in LDS) ----------------
    {
        const int jg = tid & 15;     // 16 j-groups per row
        const int m  = tid >> 4;     // 16 rows
        const float* xr = x + (row0 + m) * D;
        float s = 0.f, s2 = 0.f;
        #pragma unroll 8
        for (int it = 0; it < 32; ++it) {
            const int j = it * 64 + jg * 4;
            float4 v = *(const float4*)(xr + j);
            s  += v.x + v.y + v.z + v.w;
            s2 += v.x * v.x + v.y * v.y + v.z * v.z + v.w * v.w;
        }
        // reduce across the 16 jg lanes (low 4 bits of lane id)
        #pragma unroll
        for (int off = 1; off < 16; off <<= 1) {
            s  += __shfl_xor(s, off);
            s2 += __shfl_xor(s2, off);
        }
        const float mu   = s * (1.0f / D);
        const float var  = s2 * (1.0f / D) - mu * mu;
        const float rstd = rsqrtf(var + 1e-5f);
        #pragma unroll 4
        for (int it = 0; it < 32; ++it) {
            const int j = it * 64 + jg * 4;
            float4 v = *(const float4*)(xr + j);
            float4 g = *(const float4*)(gamma + j);
            float4 b = *(const float4*)(beta + j);
            float h0 = (v.x - mu) * rstd * g.x + b.x;
            float h1 = (v.y - mu) * rstd * g.y + b.y;
            float h2 = (v.z - mu) * rstd * g.z + b.z;
            float h3 = (v.w - mu) * rstd * g.w + b.w;
            uint2 p;
            p.x = f2bf(h0) | (f2bf(h1) << 16);
            p.y = f2bf(h2) | (f2bf(h3) << 16);
            *(uint2*)(hs + m * HSSU + (j >> 1)) = p;
        }
    }
    __syncthreads();

    // ---------------- Phase B: down-proj  y = h @ wd ----------------
    {
        const int rg = tid & 7;          // 8 groups x 4 r
        const int mg = (tid >> 3) & 3;   // 4 groups x 4 rows
        const int ks = tid >> 5;         // 8 k-splits x 256
        const int r0 = rg * 4;
        const int m0 = mg * 4;

        float4 acc4[4];
        #pragma unroll
        for (int i = 0; i < 4; ++i) acc4[i] = make_float4(0.f, 0.f, 0.f, 0.f);

        const int kbeg = ks * 256;
        for (int k = kbeg; k < kbeg + 256; k += 4) {
            const float4* wp = (const float4*)(wd + k * NR + r0);
            float4 w0 = wp[0];
            float4 w1 = wp[8];       // +1 k-row (32 floats)
            float4 w2 = wp[16];
            float4 w3 = wp[24];
            #pragma unroll
            for (int i = 0; i < 4; ++i) {
                uint2 hp = *(const uint2*)(hs + (m0 + i) * HSSU + (k >> 1));
                fma4(bflo(hp.x), w0, acc4[i]);
                fma4(bfhi(hp.x), w1, acc4[i]);
                fma4(bflo(hp.y), w2, acc4[i]);
                fma4(bfhi(hp.y), w3, acc4[i]);
            }
        }
        #pragma unroll
        for (int i = 0; i < 4; ++i) {
            float* yp = &yacc[(m0 + i) * NR + r0];
            atomicAdd(yp + 0, acc4[i].x);
            atomicAdd(yp + 1, acc4[i].y);
            atomicAdd(yp + 2, acc4[i].z);
            atomicAdd(yp + 3, acc4[i].w);
        }
    }
    __syncthreads();

    // ---------------- GELU (exact) ----------------
    {
        #pragma unroll
        for (int e = 0; e < 2; ++e) {
            const int idx = tid + e * 256;
            const float v = yacc[idx] + bd[idx & (NR - 1)];
            amat[idx] = 0.5f * v * (1.0f + erff(v * 0.70710678118654752f));
        }
    }
    __syncthreads();

    // ---------------- Phase C: up-proj + residual ----------------
    {
        const int jg = tid & 63;     // wave = 64 consecutive j-chunks of one row-group
        const int mg = tid >> 6;     // 4 row-groups x 4 rows
        const int m0 = mg * 4;
        for (int jt = 0; jt < 4; ++jt) {
            const int j0 = jt * 512 + jg * 8;
            float4 bua = *(const float4*)(bu + j0);
            float4 bub = *(const float4*)(bu + j0 + 4);
            float4 oa[4], ob[4];
            #pragma unroll
            for (int i = 0; i < 4; ++i) {
                const float* xr = x + (row0 + m0 + i) * D + j0;
                float4 xa = *(const float4*)(xr);
                float4 xb = *(const float4*)(xr + 4);
                oa[i] = make_float4(xa.x + bua.x, xa.y + bua.y, xa.z + bua.z, xa.w + bua.w);
                ob[i] = make_float4(xb.x + bub.x, xb.y + bub.y, xb.z + bub.z, xb.w + bub.w);
            }
            for (int r = 0; r < NR; r += 4) {
                float a4[4][4];
                #pragma unroll
                for (int i = 0; i < 4; ++i) {
                    float4 t = *(const float4*)(&amat[(m0 + i) * NR + r]);
                    a4[i][0] = t.x; a4[i][1] = t.y; a4[i][2] = t.z; a4[i][3] = t.w;
                }
                #pragma unroll
                for (int rr = 0; rr < 4; ++rr) {
                    const float* wr = wu + (r + rr) * D + j0;
                    float4 wa = *(const float4*)(wr);
                    float4 wb = *(const float4*)(wr + 4);
                    #pragma unroll
                    for (int i = 0; i < 4; ++i) {
                        fma4(a4[i][rr], wa, oa[i]);
                        fma4(a4[i][rr], wb, ob[i]);
                    }
                }
            }
            #pragma unroll
            for (int i = 0; i < 4; ++i) {
                float* orow = out + (row0 + m0 + i) * D + j0;
                *(float4*)(orow)     = oa[i];
                *(float4*)(orow + 4) = ob[i];
            }
        }
    }
}

extern "C" void kernel_launch(void* const* d_in, const int* in_sizes, int n_in,
                              void* d_out, int out_size, void* d_ws, size_t ws_size,
                              hipStream_t stream) {
    (void)n_in; (void)d_ws; (void)ws_size;
    const float* x     = (const float*)d_in[0];
    const float* gamma = (const float*)d_in[1];
    const float* beta  = (const float*)d_in[2];
    const float* wd    = (const float*)d_in[3];
    const float* bd    = (const float*)d_in[4];
    const float* wu    = (const float*)d_in[5];
    const float* bu    = (const float*)d_in[6];
    float* out = (float*)d_out;

    const int nrows  = in_sizes[0] / D;          // 16384
    const int blocks = nrows / MROWS;            // 1024
    hipLaunchKernelGGL(adapter_fused, dim3(blocks), dim3(256), 0, stream,
                       x, gamma, beta, wd, bd, wu, bu, out);
}